// Round 7
// baseline (16635.551 us; speedup 1.0000x reference)
//
#include <hip/hip_runtime.h>
#include <cstdint>
#include <cstddef>

// ============================================================================
// PointerNet: encoder LSTM (B=512,S=256,D=2,H=256) + autoregressive pointer
// decode with jax.random.categorical (threefry2x32 partitionable, key 42).
// Output: int32 indices [512][256], trajectory-exact vs JAX reference.
//
// R11 = R10 + WAVE-SPECIALIZED decoder overlap (R6's verified rotation, but
// concurrency across waves instead of per-thread register pipelining, which
// R6-R9 proved unimplementable under the 64-VGPR allocator pin).
// Decoder loop (prologue = LSTM step 0, din=0, Wi exact-0 skipped):
//   phase X: waves 0-7  : Wh.h_t partials -> red   (2 passes, baseline body)
//            waves 8-15 : attention(t) on h_t, 2 s/lane, gumbel, wave argmax
//   S1 | argmax + out + mask + din staging (partV/partI recompute)
//   S2 | (t==255: break)  Wi.din added onto red (16-wave baseline partition)
//   S3 | P2 activation -> h_{t+1}
//   S4
// Each SIMD: 2 FMA-heavy matmul waves + 2 load-heavy attn waves -> attention
// L3 latency hides under matmul issue. Wh partials round-trip red (f32 LDS,
// bit-exact); Wi continues the chain in baseline order -> exact trajectory.
// Live sets: matmul pass ~56 regs (== baseline P1), attn ~30, Wi ~56 -> fits
// the 64-VGPR pin, no spill. LDS identical to R4/R10 context (79360B).
// ============================================================================

typedef float v4f __attribute__((ext_vector_type(4)));

#define WS_ENCW4_OFF  (2u << 20)                    // [256 k][256 u][4 g] f32
#define WS_DECWI4_OFF (3u << 20)
#define WS_DECWH4_OFF (4u << 20)
#define WS_ENCK4_OFF  (5u << 20)                    // [512 b][64 u4][256 s][4] f32
#define WS_NEEDED     ((size_t)(5u << 20) + (size_t)512 * 64 * 256 * 16)

__device__ __forceinline__ unsigned rotl32(unsigned x, int r) {
  return (x << r) | (x >> (32 - r));
}
__device__ __forceinline__ float sigm(float x) { return 1.f / (1.f + expf(-x)); }

// Threefry-2x32, 20 rounds (jax._src.prng schedule) — verified exact R1-R10.
__device__ __forceinline__ void tf2(unsigned k0, unsigned k1,
                                    unsigned& x0, unsigned& x1) {
  const unsigned k2 = k0 ^ k1 ^ 0x1BD11BDAu;
  x0 += k0; x1 += k1;
  x0 += x1; x1 = rotl32(x1, 13); x1 ^= x0;
  x0 += x1; x1 = rotl32(x1, 15); x1 ^= x0;
  x0 += x1; x1 = rotl32(x1, 26); x1 ^= x0;
  x0 += x1; x1 = rotl32(x1,  6); x1 ^= x0;
  x0 += k1; x1 += k2 + 1u;
  x0 += x1; x1 = rotl32(x1, 17); x1 ^= x0;
  x0 += x1; x1 = rotl32(x1, 29); x1 ^= x0;
  x0 += x1; x1 = rotl32(x1, 16); x1 ^= x0;
  x0 += x1; x1 = rotl32(x1, 24); x1 ^= x0;
  x0 += k2; x1 += k0 + 2u;
  x0 += x1; x1 = rotl32(x1, 13); x1 ^= x0;
  x0 += x1; x1 = rotl32(x1, 15); x1 ^= x0;
  x0 += x1; x1 = rotl32(x1, 26); x1 ^= x0;
  x0 += x1; x1 = rotl32(x1,  6); x1 ^= x0;
  x0 += k0; x1 += k1 + 3u;
  x0 += x1; x1 = rotl32(x1, 17); x1 ^= x0;
  x0 += x1; x1 = rotl32(x1, 29); x1 ^= x0;
  x0 += x1; x1 = rotl32(x1, 16); x1 ^= x0;
  x0 += x1; x1 = rotl32(x1, 24); x1 ^= x0;
  x0 += k1; x1 += k2 + 4u;
  x0 += x1; x1 = rotl32(x1, 13); x1 ^= x0;
  x0 += x1; x1 = rotl32(x1, 15); x1 ^= x0;
  x0 += x1; x1 = rotl32(x1, 26); x1 ^= x0;
  x0 += x1; x1 = rotl32(x1,  6); x1 ^= x0;
  x0 += k2; x1 += k0 + 5u;
}

// Repack W [1024 rows][256 k] row-major -> [k][u][gate] (float4 per (k,u)).
__global__ void repack_k(const float* __restrict__ eWh,
                         const float* __restrict__ dWi,
                         const float* __restrict__ dWh,
                         float* __restrict__ ws) {
  float* encW4 = (float*)((char*)ws + WS_ENCW4_OFF);
  float* decWi4 = (float*)((char*)ws + WS_DECWI4_OFF);
  float* decWh4 = (float*)((char*)ws + WS_DECWH4_OFF);
  const int n = blockIdx.x * blockDim.x + threadIdx.x;   // 65536 = 256k x 256u
  if (n >= 65536) return;
  const int k = n >> 8, u = n & 255;
#pragma unroll
  for (int g = 0; g < 4; ++g) {
    const int src = ((g << 8) + u) * 256 + k;
    const int dst = (n << 2) + g;
    encW4[dst] = eWh[src];
    decWi4[dst] = dWi[src];
    decWh4[dst] = dWh[src];
  }
}

__global__ void __launch_bounds__(1024)
ptrnet_kernel(const float* __restrict__ inp,    // [512][256][2]
              const float* __restrict__ eWi,    // [1024][2]
              const float* __restrict__ eBi, const float* __restrict__ eBh,
              const float* __restrict__ dBi, const float* __restrict__ dBh,
              int* __restrict__ out,            // [512][256]
              float* __restrict__ ws) {
  const int tid  = threadIdx.x;
  const int wave = tid >> 6, l = tid & 63;
  const int kq   = wave >> 2;               // baseline partition (enc P1, Wi)
  const int uw   = wave & 3;
  const int uP   = (uw << 6) | l;
  const int k4b  = kq << 4;
  const int bA   = tid >> 8;                // P2/argmax partition
  const int uA   = tid & 255;
  const int b0   = blockIdx.x << 2;
  const int bG   = b0 + bA;

  // phase-X matmul partition (waves 0-7): kq x u-half, 2 passes of 64 u
  const int kqM  = wave >> 1;               // 0..3 (valid for wave<8)
  const int k4bM = kqM << 4;
  const int uM0  = ((wave & 1) << 7) | l;   // pass-0 unit
  // phase-X attention partition (waves 8-15): batch x s-half, 2 s per lane
  const int aw   = wave - 8;
  const int bA2  = aw >> 1;                 // 0..3 (valid for wave>=8)
  const int bG2  = b0 + bA2;
  const int s0   = ((aw & 1) << 7) | (l << 1);
  const int s1   = s0 + 1;

  const v4f* encW4  = (const v4f*)((char*)ws + WS_ENCW4_OFF);
  const v4f* decWi4 = (const v4f*)((char*)ws + WS_DECWI4_OFF);
  const v4f* decWh4 = (const v4f*)((char*)ws + WS_DECWH4_OFF);
  v4f* encK4 = (v4f*)((char*)ws + WS_ENCK4_OFF);

  __shared__ __align__(16) float hsF[2][1024];   // h dbuf: [buf][b*256+u]
  __shared__ __align__(16) v4f dinV[256];        // dec_in [b][64 k4]
  __shared__ __align__(16) v4f red[16][256];     // partials [kq*4+b][u] (gates)
  __shared__ unsigned char maskC[4][256];
  __shared__ float partV[4][2];
  __shared__ int   partI[4][2];

  // ---- activation-thread constants (keyed by uA) ----
  const float ebi_ = eBi[uA] + eBh[uA];
  const float ebf_ = eBi[256 + uA] + eBh[256 + uA];
  const float ebg_ = eBi[512 + uA] + eBh[512 + uA];
  const float ebo_ = eBi[768 + uA] + eBh[768 + uA];
  const float wxi0 = eWi[2 * uA], wxi1 = eWi[2 * uA + 1];
  const float wxf0 = eWi[2 * (256 + uA)], wxf1 = eWi[2 * (256 + uA) + 1];
  const float wxg0 = eWi[2 * (512 + uA)], wxg1 = eWi[2 * (512 + uA) + 1];
  const float wxo0 = eWi[2 * (768 + uA)], wxo1 = eWi[2 * (768 + uA) + 1];

  hsF[0][tid] = 0.f;
  __syncthreads();

  float c = 0.f;        // cell state for (bG, uA) — register-resident throughout
  int p = 0;

  // ---------------- encoder: 256 steps (R4-exact) ----------------
  for (int t = 0; t < 256; ++t) {
    v4f a0 = (v4f)0.f, a1 = (v4f)0.f, a2 = (v4f)0.f, a3 = (v4f)0.f;
    const v4f* Wp = encW4 + uP;
    const v4f* hq = (const v4f*)&hsF[p][0];       // [4 b][64 k4]
#pragma unroll 2
    for (int kk = 0; kk < 16; ++kk) {
      const int k4 = k4b + kk;
      const v4f w0 = Wp[(k4 * 4 + 0) << 8];
      const v4f w1 = Wp[(k4 * 4 + 1) << 8];
      const v4f w2 = Wp[(k4 * 4 + 2) << 8];
      const v4f w3 = Wp[(k4 * 4 + 3) << 8];
      const v4f h0 = hq[k4];
      const v4f h1 = hq[64 + k4];
      const v4f h2 = hq[128 + k4];
      const v4f h3 = hq[192 + k4];
      a0 += w0 * h0.x + w1 * h0.y + w2 * h0.z + w3 * h0.w;
      a1 += w0 * h1.x + w1 * h1.y + w2 * h1.z + w3 * h1.w;
      a2 += w0 * h2.x + w1 * h2.y + w2 * h2.z + w3 * h2.w;
      a3 += w0 * h3.x + w1 * h3.y + w2 * h3.z + w3 * h3.w;
    }
    red[(kq << 2) | 0][uP] = a0;
    red[(kq << 2) | 1][uP] = a1;
    red[(kq << 2) | 2][uP] = a2;
    red[(kq << 2) | 3][uP] = a3;
    __syncthreads();                              // S_B: partials ready
    const v4f gv = red[bA][uA] + red[4 + bA][uA] + red[8 + bA][uA] + red[12 + bA][uA];
    const float2 xv = *(const float2*)(inp + (((bG) << 8) + t) * 2);
    const float ai = gv.x + ebi_ + wxi0 * xv.x + wxi1 * xv.y;
    const float af = gv.y + ebf_ + wxf0 * xv.x + wxf1 * xv.y;
    const float ag = gv.z + ebg_ + wxg0 * xv.x + wxg1 * xv.y;
    const float ao = gv.w + ebo_ + wxo0 * xv.x + wxo1 * xv.y;
    const float iv = sigm(ai), fv = sigm(af), gva = tanhf(ag), ov = sigm(ao);
    c = fv * c + iv * gva;
    const float hn = ov * tanhf(c);
    hsF[p ^ 1][(bA << 8) | uA] = hn;
    ((float*)encK4)[(((bG << 6) + (uA >> 2)) << 10) + (t << 2) + (uA & 3)] = hn;
    __syncthreads();                              // S_C: new h ready
    p ^= 1;
  }

  // ---------------- decoder ----------------
  const float dbi_ = dBi[uA] + dBh[uA];
  const float dbf_ = dBi[256 + uA] + dBh[256 + uA];
  const float dbg_ = dBi[512 + uA] + dBh[512 + uA];
  const float dbo_ = dBi[768 + uA] + dBh[768 + uA];
  const float NEG_INF = __int_as_float((int)0xff800000);

  maskC[bA][uA] = 0;
  if (tid < 256) dinV[tid] = (v4f)0.f;
  __syncthreads();

  // ---- prologue: LSTM step 0 (din = 0 -> Wi contributes exact 0, skipped;
  //      baseline 16-wave partition; verified R6-R9) ----
  {
    v4f a0 = (v4f)0.f, a1 = (v4f)0.f, a2 = (v4f)0.f, a3 = (v4f)0.f;
    const v4f* Wh = decWh4 + uP;
    const v4f* hq = (const v4f*)&hsF[p][0];
#pragma unroll 2
    for (int kk = 0; kk < 16; ++kk) {
      const int k4 = k4b + kk;
      const v4f w0 = Wh[(k4 * 4 + 0) << 8];
      const v4f w1 = Wh[(k4 * 4 + 1) << 8];
      const v4f w2 = Wh[(k4 * 4 + 2) << 8];
      const v4f w3 = Wh[(k4 * 4 + 3) << 8];
      const v4f h0 = hq[k4];
      const v4f h1 = hq[64 + k4];
      const v4f h2 = hq[128 + k4];
      const v4f h3 = hq[192 + k4];
      a0 += w0 * h0.x + w1 * h0.y + w2 * h0.z + w3 * h0.w;
      a1 += w0 * h1.x + w1 * h1.y + w2 * h1.z + w3 * h1.w;
      a2 += w0 * h2.x + w1 * h2.y + w2 * h2.z + w3 * h2.w;
      a3 += w0 * h3.x + w1 * h3.y + w2 * h3.z + w3 * h3.w;
    }
    red[(kq << 2) | 0][uP] = a0;
    red[(kq << 2) | 1][uP] = a1;
    red[(kq << 2) | 2][uP] = a2;
    red[(kq << 2) | 3][uP] = a3;
    __syncthreads();
    const v4f gv = red[bA][uA] + red[4 + bA][uA] + red[8 + bA][uA] + red[12 + bA][uA];
    const float iv = sigm(gv.x + dbi_), fv = sigm(gv.y + dbf_);
    const float gva = tanhf(gv.z + dbg_), ov = sigm(gv.w + dbo_);
    c = fv * c + iv * gva;
    const float hn = ov * tanhf(c);
    hsF[p ^ 1][(bA << 8) | uA] = hn;
    __syncthreads();
    p ^= 1;                                       // hsF[p] = h_0
  }

  for (int t = 0; t < 256; ++t) {
    // ======== phase X: waves 0-7 Wh·h_t  ∥  waves 8-15 attention(t) ========
    if (wave < 8) {
      const v4f* hq = (const v4f*)&hsF[p][0];
#pragma unroll
      for (int pass = 0; pass < 2; ++pass) {
        const int uMp = uM0 + (pass << 6);
        v4f a0 = (v4f)0.f, a1 = (v4f)0.f, a2 = (v4f)0.f, a3 = (v4f)0.f;
        const v4f* Wh = decWh4 + uMp;
#pragma unroll 2
        for (int kk = 0; kk < 16; ++kk) {
          const int k4 = k4bM + kk;
          const v4f w0 = Wh[(k4 * 4 + 0) << 8];
          const v4f w1 = Wh[(k4 * 4 + 1) << 8];
          const v4f w2 = Wh[(k4 * 4 + 2) << 8];
          const v4f w3 = Wh[(k4 * 4 + 3) << 8];
          const v4f h0 = hq[k4];
          const v4f h1 = hq[64 + k4];
          const v4f h2 = hq[128 + k4];
          const v4f h3 = hq[192 + k4];
          a0 += w0 * h0.x + w1 * h0.y + w2 * h0.z + w3 * h0.w;
          a1 += w0 * h1.x + w1 * h1.y + w2 * h1.z + w3 * h1.w;
          a2 += w0 * h2.x + w1 * h2.y + w2 * h2.z + w3 * h2.w;
          a3 += w0 * h3.x + w1 * h3.y + w2 * h3.z + w3 * h3.w;
        }
        red[(kqM << 2) | 0][uMp] = a0;
        red[(kqM << 2) | 1][uMp] = a1;
        red[(kqM << 2) | 2][uMp] = a2;
        red[(kqM << 2) | 3][uMp] = a3;
      }
    } else {
      // attention for s0, s1 (adjacent) of batch bA2 on h_t
      const int m0 = maskC[bA2][s0];
      const int m1 = maskC[bA2][s1];
      const v4f* E0 = encK4 + (bG2 << 14) + s0;   // s stride = 1 v4f
      const v4f* hq2 = ((const v4f*)&hsF[p][0]) + (bA2 << 6);
      float sc0 = 0.f, sc1 = 0.f;
#pragma unroll 2
      for (int k4 = 0; k4 < 64; ++k4) {
        const v4f hv = hq2[k4];
        if (!m0) {
          const v4f ev = E0[k4 << 8];
          sc0 += ev.x * hv.x + ev.y * hv.y + ev.z * hv.z + ev.w * hv.w;
        }
        if (!m1) {
          const v4f ev = E0[(k4 << 8) + 1];
          sc1 += ev.x * hv.x + ev.y * hv.y + ev.z * hv.z + ev.w * hv.w;
        }
      }
      // gumbel for both s (threefry key shared per t)
      unsigned kk0 = 0u, kk1 = (unsigned)t;
      tf2(0u, 42u, kk0, kk1);
      float g0, g1;
      {
        unsigned y0 = 0u, y1 = (unsigned)((bG2 << 8) + s0);
        tf2(kk0, kk1, y0, y1);
        const unsigned bits = y0 ^ y1;
        const float fr = __uint_as_float((bits >> 9) | 0x3f800000u) - 1.0f;
        const float uu = (fr > 0.f) ? fr : 1.17549435e-38f;
        g0 = -logf(-logf(uu));
      }
      {
        unsigned y0 = 0u, y1 = (unsigned)((bG2 << 8) + s1);
        tf2(kk0, kk1, y0, y1);
        const unsigned bits = y0 ^ y1;
        const float fr = __uint_as_float((bits >> 9) | 0x3f800000u) - 1.0f;
        const float uu = (fr > 0.f) ? fr : 1.17549435e-38f;
        g1 = -logf(-logf(uu));
      }
      const float v0 = m0 ? NEG_INF : (sc0 + g0);
      const float v1 = m1 ? NEG_INF : (sc1 + g1);
      float bv = v0; int bi = s0;
      if (v1 > bv) { bv = v1; bi = s1; }          // equality keeps lower s
#pragma unroll
      for (int off = 32; off; off >>= 1) {
        const float ov2 = __shfl_xor(bv, off, 64);
        const int oi2 = __shfl_xor(bi, off, 64);
        if (ov2 > bv || (ov2 == bv && oi2 < bi)) { bv = ov2; bi = oi2; }
      }
      if (l == 0) { partV[bA2][aw & 1] = bv; partI[bA2][aw & 1] = bi; }
    }
    __syncthreads();                              // S1: red-Wh + partV ready

    // final argmax (redundant per thread), out/mask, din staging
    float v = partV[bA][0]; int fi = partI[bA][0];
    {
      const float vj = partV[bA][1];
      if (vj > v) { v = vj; fi = partI[bA][1]; }  // strict > keeps lowest s
    }
    if (uA == 0) out[(bG << 8) + t] = fi;
    if (uA == fi) maskC[bA][uA] = 1;
    if (tid < 256) {                              // stage din_{t+1}
      const int bb = tid >> 6, k4s = tid & 63;
      float v2 = partV[bb][0]; int fib = partI[bb][0];
      {
        const float vj = partV[bb][1];
        if (vj > v2) { v2 = vj; fib = partI[bb][1]; }
      }
      dinV[tid] = encK4[((((b0 + bb) << 6) | k4s) << 8) + fib];
    }
    __syncthreads();                              // S2: din/mask ready

    if (t == 255) break;                          // last index emitted

    // ======== Wi·din sweep: 16 waves, continue the chain from red ========
    {
      v4f a0 = red[(kq << 2) | 0][uP];
      v4f a1 = red[(kq << 2) | 1][uP];
      v4f a2 = red[(kq << 2) | 2][uP];
      v4f a3 = red[(kq << 2) | 3][uP];
      const v4f* Wi = decWi4 + uP;
#pragma unroll 2
      for (int kk = 0; kk < 16; ++kk) {
        const int k4 = k4b + kk;
        const v4f w0 = Wi[(k4 * 4 + 0) << 8];
        const v4f w1 = Wi[(k4 * 4 + 1) << 8];
        const v4f w2 = Wi[(k4 * 4 + 2) << 8];
        const v4f w3 = Wi[(k4 * 4 + 3) << 8];
        const v4f d0 = dinV[k4];
        const v4f d1 = dinV[64 + k4];
        const v4f d2 = dinV[128 + k4];
        const v4f d3 = dinV[192 + k4];
        a0 += w0 * d0.x + w1 * d0.y + w2 * d0.z + w3 * d0.w;
        a1 += w0 * d1.x + w1 * d1.y + w2 * d1.z + w3 * d1.w;
        a2 += w0 * d2.x + w1 * d2.y + w2 * d2.z + w3 * d2.w;
        a3 += w0 * d3.x + w1 * d3.y + w2 * d3.z + w3 * d3.w;
      }
      red[(kq << 2) | 0][uP] = a0;
      red[(kq << 2) | 1][uP] = a1;
      red[(kq << 2) | 2][uP] = a2;
      red[(kq << 2) | 3][uP] = a3;
    }
    __syncthreads();                              // S3: full partials ready

    // ======== P2: activation -> h_{t+1} ========
    const v4f gv = red[bA][uA] + red[4 + bA][uA] + red[8 + bA][uA] + red[12 + bA][uA];
    const float iv = sigm(gv.x + dbi_), fv = sigm(gv.y + dbf_);
    const float gva = tanhf(gv.z + dbg_), ov = sigm(gv.w + dbo_);
    c = fv * c + iv * gva;
    const float hn = ov * tanhf(c);
    hsF[p ^ 1][(bA << 8) | uA] = hn;
    __syncthreads();                              // S4: h_{t+1} ready
    p ^= 1;
  }
}

extern "C" void kernel_launch(void* const* d_in, const int* in_sizes, int n_in,
                              void* d_out, int out_size, void* d_ws, size_t ws_size,
                              hipStream_t stream) {
  (void)in_sizes; (void)n_in; (void)out_size;
  if (ws_size < WS_NEEDED) return;   // need ~139 MB scratch

  const float* inp = (const float*)d_in[0];
  const float* eWi = (const float*)d_in[1];
  const float* eWh = (const float*)d_in[2];
  const float* eBi = (const float*)d_in[3];
  const float* eBh = (const float*)d_in[4];
  const float* dWi = (const float*)d_in[5];
  const float* dWh = (const float*)d_in[6];
  const float* dBi = (const float*)d_in[7];
  const float* dBh = (const float*)d_in[8];
  int* out = (int*)d_out;
  float* wsf = (float*)d_ws;

  hipLaunchKernelGGL(repack_k, dim3(256), dim3(256), 0, stream, eWh, dWi, dWh, wsf);
  hipLaunchKernelGGL(ptrnet_kernel, dim3(128), dim3(1024), 0, stream,
                     inp, eWi, eBi, eBh, dBi, dBh, out, wsf);
}

// Round 8
// 12847.797 us; speedup vs baseline: 1.2948x; 1.2948x over previous
//
#include <hip/hip_runtime.h>
#include <cstdint>
#include <cstddef>

// ============================================================================
// PointerNet: encoder LSTM (B=512,S=256,D=2,H=256) + autoregressive pointer
// decode with jax.random.categorical (threefry2x32 partitionable, key 42).
// Output: int32 indices [512][256], trajectory-exact vs JAX reference.
//
// R12 = R10 + attention FUSED into the Wh sweep (R6 rotation, fusion form).
// Evidence: FETCH_SIZE 17.5GB == the attention E-stream (encK4, 0.53MB/block/
// step); decoder step = weight stream (L2, ~7us) + E stream (L3, ~4-6us) run
// SERIALLY. R6's rotation proved attn(t) and Wh.h_t are independent given h_t
// (passed 4x), but register pipelining spills (64-VGPR pin, R6-R9) and wave
// specialization kills MLP (R11, -42%). Fusion: each Wh kk iteration carries
// 4 attention k4 terms, load-and-consume (transient ev, ~6 extra regs). TLP
// (4 waves/SIMD) hides E latency -- same mechanism as R4's standalone attn
// phase -- while both memory streams flow concurrently.
//  * sc accumulates k4=0..63 in order; Wh/Wi chains in R4 order; rotation
//    dataflow identical to R6 (verified) -> bit-identical trajectory.
//  * 4 barriers/decoder step; prologue = LSTM step 0 (din=0, Wi exact-0).
// ============================================================================

typedef float v4f __attribute__((ext_vector_type(4)));

#define WS_ENCW4_OFF  (2u << 20)                    // [256 k][256 u][4 g] f32
#define WS_DECWI4_OFF (3u << 20)
#define WS_DECWH4_OFF (4u << 20)
#define WS_ENCK4_OFF  (5u << 20)                    // [512 b][64 u4][256 s][4] f32
#define WS_NEEDED     ((size_t)(5u << 20) + (size_t)512 * 64 * 256 * 16)

__device__ __forceinline__ unsigned rotl32(unsigned x, int r) {
  return (x << r) | (x >> (32 - r));
}
__device__ __forceinline__ float sigm(float x) { return 1.f / (1.f + expf(-x)); }

// Threefry-2x32, 20 rounds (jax._src.prng schedule) — verified exact R1-R11.
__device__ __forceinline__ void tf2(unsigned k0, unsigned k1,
                                    unsigned& x0, unsigned& x1) {
  const unsigned k2 = k0 ^ k1 ^ 0x1BD11BDAu;
  x0 += k0; x1 += k1;
  x0 += x1; x1 = rotl32(x1, 13); x1 ^= x0;
  x0 += x1; x1 = rotl32(x1, 15); x1 ^= x0;
  x0 += x1; x1 = rotl32(x1, 26); x1 ^= x0;
  x0 += x1; x1 = rotl32(x1,  6); x1 ^= x0;
  x0 += k1; x1 += k2 + 1u;
  x0 += x1; x1 = rotl32(x1, 17); x1 ^= x0;
  x0 += x1; x1 = rotl32(x1, 29); x1 ^= x0;
  x0 += x1; x1 = rotl32(x1, 16); x1 ^= x0;
  x0 += x1; x1 = rotl32(x1, 24); x1 ^= x0;
  x0 += k2; x1 += k0 + 2u;
  x0 += x1; x1 = rotl32(x1, 13); x1 ^= x0;
  x0 += x1; x1 = rotl32(x1, 15); x1 ^= x0;
  x0 += x1; x1 = rotl32(x1, 26); x1 ^= x0;
  x0 += x1; x1 = rotl32(x1,  6); x1 ^= x0;
  x0 += k0; x1 += k1 + 3u;
  x0 += x1; x1 = rotl32(x1, 17); x1 ^= x0;
  x0 += x1; x1 = rotl32(x1, 29); x1 ^= x0;
  x0 += x1; x1 = rotl32(x1, 16); x1 ^= x0;
  x0 += x1; x1 = rotl32(x1, 24); x1 ^= x0;
  x0 += k1; x1 += k2 + 4u;
  x0 += x1; x1 = rotl32(x1, 13); x1 ^= x0;
  x0 += x1; x1 = rotl32(x1, 15); x1 ^= x0;
  x0 += x1; x1 = rotl32(x1, 26); x1 ^= x0;
  x0 += x1; x1 = rotl32(x1,  6); x1 ^= x0;
  x0 += k2; x1 += k0 + 5u;
}

// Repack W [1024 rows][256 k] row-major -> [k][u][gate] (float4 per (k,u)).
__global__ void repack_k(const float* __restrict__ eWh,
                         const float* __restrict__ dWi,
                         const float* __restrict__ dWh,
                         float* __restrict__ ws) {
  float* encW4 = (float*)((char*)ws + WS_ENCW4_OFF);
  float* decWi4 = (float*)((char*)ws + WS_DECWI4_OFF);
  float* decWh4 = (float*)((char*)ws + WS_DECWH4_OFF);
  const int n = blockIdx.x * blockDim.x + threadIdx.x;   // 65536 = 256k x 256u
  if (n >= 65536) return;
  const int k = n >> 8, u = n & 255;
#pragma unroll
  for (int g = 0; g < 4; ++g) {
    const int src = ((g << 8) + u) * 256 + k;
    const int dst = (n << 2) + g;
    encW4[dst] = eWh[src];
    decWi4[dst] = dWi[src];
    decWh4[dst] = dWh[src];
  }
}

__global__ void __launch_bounds__(1024)
ptrnet_kernel(const float* __restrict__ inp,    // [512][256][2]
              const float* __restrict__ eWi,    // [1024][2]
              const float* __restrict__ eBi, const float* __restrict__ eBh,
              const float* __restrict__ dBi, const float* __restrict__ dBh,
              int* __restrict__ out,            // [512][256]
              float* __restrict__ ws) {
  const int tid  = threadIdx.x;
  const int wave = tid >> 6, l = tid & 63;
  const int kq   = wave >> 2;               // K-quarter 0..3 (16 k4 each)
  const int uw   = wave & 3;                // u-slice 0..3
  const int uP   = (uw << 6) | l;           // this lane's unit in P1 (matmul)
  const int k4b  = kq << 4;
  const int bA   = tid >> 8;                // this thread's batch in P2/attn
  const int uA   = tid & 255;               // this thread's unit/score in P2/attn
  const int b0   = blockIdx.x << 2;
  const int bG   = b0 + bA;

  const v4f* encW4  = (const v4f*)((char*)ws + WS_ENCW4_OFF);
  const v4f* decWi4 = (const v4f*)((char*)ws + WS_DECWI4_OFF);
  const v4f* decWh4 = (const v4f*)((char*)ws + WS_DECWH4_OFF);
  v4f* encK4 = (v4f*)((char*)ws + WS_ENCK4_OFF);

  __shared__ __align__(16) float hsF[2][1024];   // h dbuf: [buf][b*256+u]
  __shared__ __align__(16) v4f dinV[256];        // dec_in [b][64 k4]
  __shared__ __align__(16) v4f red[16][256];     // partials [kq*4+b][u] (gates)
  __shared__ unsigned char maskC[4][256];
  __shared__ float partV[4][4];
  __shared__ int   partI[4][4];

  // ---- activation-thread constants (keyed by uA) ----
  const float ebi_ = eBi[uA] + eBh[uA];
  const float ebf_ = eBi[256 + uA] + eBh[256 + uA];
  const float ebg_ = eBi[512 + uA] + eBh[512 + uA];
  const float ebo_ = eBi[768 + uA] + eBh[768 + uA];
  const float wxi0 = eWi[2 * uA], wxi1 = eWi[2 * uA + 1];
  const float wxf0 = eWi[2 * (256 + uA)], wxf1 = eWi[2 * (256 + uA) + 1];
  const float wxg0 = eWi[2 * (512 + uA)], wxg1 = eWi[2 * (512 + uA) + 1];
  const float wxo0 = eWi[2 * (768 + uA)], wxo1 = eWi[2 * (768 + uA) + 1];

  hsF[0][tid] = 0.f;
  __syncthreads();

  float c = 0.f;        // cell state for (bG, uA) — register-resident throughout
  int p = 0;

  // ---------------- encoder: 256 steps (R4-exact) ----------------
  for (int t = 0; t < 256; ++t) {
    v4f a0 = (v4f)0.f, a1 = (v4f)0.f, a2 = (v4f)0.f, a3 = (v4f)0.f;
    const v4f* Wp = encW4 + uP;
    const v4f* hq = (const v4f*)&hsF[p][0];       // [4 b][64 k4]
#pragma unroll 2
    for (int kk = 0; kk < 16; ++kk) {
      const int k4 = k4b + kk;
      const v4f w0 = Wp[(k4 * 4 + 0) << 8];
      const v4f w1 = Wp[(k4 * 4 + 1) << 8];
      const v4f w2 = Wp[(k4 * 4 + 2) << 8];
      const v4f w3 = Wp[(k4 * 4 + 3) << 8];
      const v4f h0 = hq[k4];
      const v4f h1 = hq[64 + k4];
      const v4f h2 = hq[128 + k4];
      const v4f h3 = hq[192 + k4];
      a0 += w0 * h0.x + w1 * h0.y + w2 * h0.z + w3 * h0.w;
      a1 += w0 * h1.x + w1 * h1.y + w2 * h1.z + w3 * h1.w;
      a2 += w0 * h2.x + w1 * h2.y + w2 * h2.z + w3 * h2.w;
      a3 += w0 * h3.x + w1 * h3.y + w2 * h3.z + w3 * h3.w;
    }
    red[(kq << 2) | 0][uP] = a0;
    red[(kq << 2) | 1][uP] = a1;
    red[(kq << 2) | 2][uP] = a2;
    red[(kq << 2) | 3][uP] = a3;
    __syncthreads();                              // S_B: partials ready
    const v4f gv = red[bA][uA] + red[4 + bA][uA] + red[8 + bA][uA] + red[12 + bA][uA];
    const float2 xv = *(const float2*)(inp + (((bG) << 8) + t) * 2);
    const float ai = gv.x + ebi_ + wxi0 * xv.x + wxi1 * xv.y;
    const float af = gv.y + ebf_ + wxf0 * xv.x + wxf1 * xv.y;
    const float ag = gv.z + ebg_ + wxg0 * xv.x + wxg1 * xv.y;
    const float ao = gv.w + ebo_ + wxo0 * xv.x + wxo1 * xv.y;
    const float iv = sigm(ai), fv = sigm(af), gva = tanhf(ag), ov = sigm(ao);
    c = fv * c + iv * gva;
    const float hn = ov * tanhf(c);
    hsF[p ^ 1][(bA << 8) | uA] = hn;
    ((float*)encK4)[(((bG << 6) + (uA >> 2)) << 10) + (t << 2) + (uA & 3)] = hn;
    __syncthreads();                              // S_C: new h ready
    p ^= 1;
  }

  // ---------------- decoder: rotated schedule, fused attn ----------------
  const float dbi_ = dBi[uA] + dBh[uA];
  const float dbf_ = dBi[256 + uA] + dBh[256 + uA];
  const float dbg_ = dBi[512 + uA] + dBh[512 + uA];
  const float dbo_ = dBi[768 + uA] + dBh[768 + uA];
  const float NEG_INF = __int_as_float((int)0xff800000);

  maskC[bA][uA] = 0;
  if (tid < 256) dinV[tid] = (v4f)0.f;
  __syncthreads();

  // ---- prologue: LSTM step 0 (din = 0 -> Wi contributes exact 0, skipped) ----
  {
    v4f a0 = (v4f)0.f, a1 = (v4f)0.f, a2 = (v4f)0.f, a3 = (v4f)0.f;
    const v4f* Wh = decWh4 + uP;
    const v4f* hq = (const v4f*)&hsF[p][0];
#pragma unroll 2
    for (int kk = 0; kk < 16; ++kk) {
      const int k4 = k4b + kk;
      const v4f w0 = Wh[(k4 * 4 + 0) << 8];
      const v4f w1 = Wh[(k4 * 4 + 1) << 8];
      const v4f w2 = Wh[(k4 * 4 + 2) << 8];
      const v4f w3 = Wh[(k4 * 4 + 3) << 8];
      const v4f h0 = hq[k4];
      const v4f h1 = hq[64 + k4];
      const v4f h2 = hq[128 + k4];
      const v4f h3 = hq[192 + k4];
      a0 += w0 * h0.x + w1 * h0.y + w2 * h0.z + w3 * h0.w;
      a1 += w0 * h1.x + w1 * h1.y + w2 * h1.z + w3 * h1.w;
      a2 += w0 * h2.x + w1 * h2.y + w2 * h2.z + w3 * h2.w;
      a3 += w0 * h3.x + w1 * h3.y + w2 * h3.z + w3 * h3.w;
    }
    red[(kq << 2) | 0][uP] = a0;
    red[(kq << 2) | 1][uP] = a1;
    red[(kq << 2) | 2][uP] = a2;
    red[(kq << 2) | 3][uP] = a3;
    __syncthreads();
    const v4f gv = red[bA][uA] + red[4 + bA][uA] + red[8 + bA][uA] + red[12 + bA][uA];
    const float iv = sigm(gv.x + dbi_), fv = sigm(gv.y + dbf_);
    const float gva = tanhf(gv.z + dbg_), ov = sigm(gv.w + dbo_);
    c = fv * c + iv * gva;
    const float hn = ov * tanhf(c);
    hsF[p ^ 1][(bA << 8) | uA] = hn;
    __syncthreads();
    p ^= 1;                                       // hsF[p] = h_0
  }

  for (int t = 0; t < 256; ++t) {
    // ==== fused phase: Wh·h_t sweep (for t+1) + attention(t), both on h_t ====
    const int masked = maskC[bA][uA];
    const v4f* E   = encK4 + (bG << 14) + uA;     // s = uA, u4 stride = <<8
    const v4f* hq  = (const v4f*)&hsF[p][0];
    const v4f* hq2 = hq + (bA << 6);
    const v4f* Wh  = decWh4 + uP;
    v4f a0 = (v4f)0.f, a1 = (v4f)0.f, a2 = (v4f)0.f, a3 = (v4f)0.f;
    float sc = 0.f;
#pragma unroll 2
    for (int kk = 0; kk < 16; ++kk) {
      // Wh body — identical expressions/order to R4 -> bit-identical chain
      {
        const int k4 = k4b + kk;
        const v4f w0 = Wh[(k4 * 4 + 0) << 8];
        const v4f w1 = Wh[(k4 * 4 + 1) << 8];
        const v4f w2 = Wh[(k4 * 4 + 2) << 8];
        const v4f w3 = Wh[(k4 * 4 + 3) << 8];
        const v4f h0 = hq[k4];
        const v4f h1 = hq[64 + k4];
        const v4f h2 = hq[128 + k4];
        const v4f h3 = hq[192 + k4];
        a0 += w0 * h0.x + w1 * h0.y + w2 * h0.z + w3 * h0.w;
        a1 += w0 * h1.x + w1 * h1.y + w2 * h1.z + w3 * h1.w;
        a2 += w0 * h2.x + w1 * h2.y + w2 * h2.z + w3 * h2.w;
        a3 += w0 * h3.x + w1 * h3.y + w2 * h3.z + w3 * h3.w;
      }
      // 4 attention terms, k4a = kk*4+j (ascending 0..63 across kk -> R4 order)
      if (!masked) {
#pragma unroll
        for (int j = 0; j < 4; ++j) {
          const int k4a = (kk << 2) | j;
          const v4f ev = E[k4a << 8];
          const v4f hv = hq2[k4a];
          sc += ev.x * hv.x + ev.y * hv.y + ev.z * hv.z + ev.w * hv.w;
        }
      }
    }
    red[(kq << 2) | 0][uP] = a0;
    red[(kq << 2) | 1][uP] = a1;
    red[(kq << 2) | 2][uP] = a2;
    red[(kq << 2) | 3][uP] = a3;

    // ---- gumbel + wave argmax (thread (bA, s=uA)) ----
    unsigned bits;
    {
      unsigned kk0 = 0u, kk1 = (unsigned)t;
      tf2(0u, 42u, kk0, kk1);
      unsigned y0 = 0u, y1 = (unsigned)((bG << 8) + uA);
      tf2(kk0, kk1, y0, y1);
      bits = y0 ^ y1;
    }
    const float fr = __uint_as_float((bits >> 9) | 0x3f800000u) - 1.0f;
    const float uu = (fr > 0.f) ? fr : 1.17549435e-38f;
    const float gum = -logf(-logf(uu));
    float bv = masked ? NEG_INF : (sc + gum);
    int bi = uA;
#pragma unroll
    for (int off = 32; off; off >>= 1) {
      const float ov2 = __shfl_xor(bv, off, 64);
      const int oi2 = __shfl_xor(bi, off, 64);
      if (ov2 > bv || (ov2 == bv && oi2 < bi)) { bv = ov2; bi = oi2; }
    }
    if (l == 0) { partV[bA][uw] = bv; partI[bA][uw] = bi; }
    __syncthreads();                              // S1: red-Wh + partV ready

    // final cross-chunk argmax (redundant per thread), out/mask/din staging
    float v = partV[bA][0]; int fi = partI[bA][0];
#pragma unroll
    for (int j = 1; j < 4; ++j) {
      const float vj = partV[bA][j];
      if (vj > v) { v = vj; fi = partI[bA][j]; }   // strict > keeps lowest s
    }
    if (uA == 0) out[(bG << 8) + t] = fi;
    if (uA == fi) maskC[bA][uA] = 1;
    if (tid < 256) {                               // stage din_{t+1}
      const int bb = tid >> 6, k4s = tid & 63;
      float v2 = partV[bb][0]; int fib = partI[bb][0];
#pragma unroll
      for (int j = 1; j < 4; ++j) {
        const float vj = partV[bb][j];
        if (vj > v2) { v2 = vj; fib = partI[bb][j]; }
      }
      dinV[tid] = encK4[((((b0 + bb) << 6) | k4s) << 8) + fib];
    }
    __syncthreads();                              // S2: din/mask ready

    if (t == 255) break;                           // last index emitted

    // ==== Wi·din sweep: continue the chain from red (same-thread reload) ====
    {
      v4f b0r = red[(kq << 2) | 0][uP];
      v4f b1r = red[(kq << 2) | 1][uP];
      v4f b2r = red[(kq << 2) | 2][uP];
      v4f b3r = red[(kq << 2) | 3][uP];
      const v4f* Wi = decWi4 + uP;
#pragma unroll 2
      for (int kk = 0; kk < 16; ++kk) {
        const int k4 = k4b + kk;
        const v4f w0 = Wi[(k4 * 4 + 0) << 8];
        const v4f w1 = Wi[(k4 * 4 + 1) << 8];
        const v4f w2 = Wi[(k4 * 4 + 2) << 8];
        const v4f w3 = Wi[(k4 * 4 + 3) << 8];
        const v4f d0 = dinV[k4];
        const v4f d1 = dinV[64 + k4];
        const v4f d2 = dinV[128 + k4];
        const v4f d3 = dinV[192 + k4];
        b0r += w0 * d0.x + w1 * d0.y + w2 * d0.z + w3 * d0.w;
        b1r += w0 * d1.x + w1 * d1.y + w2 * d1.z + w3 * d1.w;
        b2r += w0 * d2.x + w1 * d2.y + w2 * d2.z + w3 * d2.w;
        b3r += w0 * d3.x + w1 * d3.y + w2 * d3.z + w3 * d3.w;
      }
      red[(kq << 2) | 0][uP] = b0r;
      red[(kq << 2) | 1][uP] = b1r;
      red[(kq << 2) | 2][uP] = b2r;
      red[(kq << 2) | 3][uP] = b3r;
    }
    __syncthreads();                              // S3: full partials ready

    // ==== P2: activation -> h_{t+1} ====
    const v4f gv = red[bA][uA] + red[4 + bA][uA] + red[8 + bA][uA] + red[12 + bA][uA];
    const float iv = sigm(gv.x + dbi_), fv = sigm(gv.y + dbf_);
    const float gva = tanhf(gv.z + dbg_), ov = sigm(gv.w + dbo_);
    c = fv * c + iv * gva;
    const float hn = ov * tanhf(c);
    hsF[p ^ 1][(bA << 8) | uA] = hn;
    __syncthreads();                              // S4: h_{t+1} ready
    p ^= 1;
  }
}

extern "C" void kernel_launch(void* const* d_in, const int* in_sizes, int n_in,
                              void* d_out, int out_size, void* d_ws, size_t ws_size,
                              hipStream_t stream) {
  (void)in_sizes; (void)n_in; (void)out_size;
  if (ws_size < WS_NEEDED) return;   // need ~139 MB scratch

  const float* inp = (const float*)d_in[0];
  const float* eWi = (const float*)d_in[1];
  const float* eWh = (const float*)d_in[2];
  const float* eBi = (const float*)d_in[3];
  const float* eBh = (const float*)d_in[4];
  const float* dWi = (const float*)d_in[5];
  const float* dWh = (const float*)d_in[6];
  const float* dBi = (const float*)d_in[7];
  const float* dBh = (const float*)d_in[8];
  int* out = (int*)d_out;
  float* wsf = (float*)d_ws;

  hipLaunchKernelGGL(repack_k, dim3(256), dim3(256), 0, stream, eWh, dWi, dWh, wsf);
  hipLaunchKernelGGL(ptrnet_kernel, dim3(128), dim3(1024), 0, stream,
                     inp, eWi, eBi, eBh, dBi, dBh, out, wsf);
}

// Round 9
// 9294.419 us; speedup vs baseline: 1.7898x; 1.3823x over previous
//
#include <hip/hip_runtime.h>
#include <cstdint>
#include <cstddef>

// ============================================================================
// PointerNet: encoder LSTM (B=512,S=256,D=2,H=256) + autoregressive pointer
// decode with jax.random.categorical (threefry2x32 partitionable, key 42).
// Output: int32 indices [512][256], trajectory-exact vs JAX reference.
//
// R13 = pairwise u-split decoder. Floor analysis (R10-R12): step time is set
// by PER-CU L2 bytes (weights 2MB + E ~0.4MB per decoder step through one
// CU's L2 port ~135GB/s), with 128/256 CUs idle. Blocks (g, g+128) pair up on
// the same 4 batches: each owns half the u-range (weights/E bytes per CU
// halve) and half the s-range for attention; all 256 CUs active.
//  * Encoder + decoder prologue: REDUNDANT in both blocks (verbatim R10 code)
//    -> bit-identical h/c in both halves, no encoder syncs, no encK4 fences
//    (each block reads only data it wrote itself or L3-resident).
//  * Decoder loop: phaseX {waves0-7 Wh.h_t (u-half) || waves8-15 attention(t)
//    (s-half)}; tagged-atomic argmax exchange; din; Wi (waves0-7); P2 (512
//    thr, u-half) + tagged-atomic h exchange.
//  * Sync = tagged u64 atomics (tag|payload in ONE word): writer atomicExch,
//    reader spins atomicAdd(p,0) at device scope. No __threadfence -> no L2
//    invalidate -> weight cache preserved. Sync region memset to 0 per launch
//    (no stale tags). 256 blocks <= 256 CUs, LDS>80KB forces 1 block/CU ->
//    all pairs co-resident, spins deadlock-free. Publish always precedes spin.
//  * Exactness: same 4-kq partial rows, same kk chains, same P2 4-term sum,
//    attention k4 0..63 serial over FULL u, same argmax tie-break -> bitwise
//    identical trajectory to R10 (verified absmax 0).
// ============================================================================

typedef float v4f __attribute__((ext_vector_type(4)));
typedef unsigned long long u64;

#define WS_HX_OFF     0u                 // [128 g][2 H][512] u64 = 1 MB
#define WS_AMX_OFF    (1u << 20)         // [128 g][2 H][8] u64 = 16 KB
#define WS_SYNC_BYTES 0x110000u
#define WS_ENCW4_OFF  (2u << 20)         // [256 k][256 u][4 g] f32
#define WS_DECWI4_OFF (3u << 20)
#define WS_DECWH4_OFF (4u << 20)
#define WS_ENCK4_OFF  (5u << 20)         // [512 b][64 u4][256 s][4] f32
#define WS_NEEDED     ((size_t)(5u << 20) + (size_t)512 * 64 * 256 * 16)

__device__ __forceinline__ unsigned rotl32(unsigned x, int r) {
  return (x << r) | (x >> (32 - r));
}
__device__ __forceinline__ float sigm(float x) { return 1.f / (1.f + expf(-x)); }

__device__ __forceinline__ u64 pk(unsigned tag, unsigned payload) {
  return ((u64)tag << 32) | (u64)payload;
}
// device-scope atomic read (resolves at coherence point; no stale L2)
__device__ __forceinline__ unsigned spinrd(u64* p, unsigned tag) {
  u64 v = atomicAdd(p, 0ull);
  while ((unsigned)(v >> 32) != tag) {
    __builtin_amdgcn_s_sleep(2);
    v = atomicAdd(p, 0ull);
  }
  return (unsigned)v;
}

// Threefry-2x32, 20 rounds (jax._src.prng schedule) — verified exact R1-R12.
__device__ __forceinline__ void tf2(unsigned k0, unsigned k1,
                                    unsigned& x0, unsigned& x1) {
  const unsigned k2 = k0 ^ k1 ^ 0x1BD11BDAu;
  x0 += k0; x1 += k1;
  x0 += x1; x1 = rotl32(x1, 13); x1 ^= x0;
  x0 += x1; x1 = rotl32(x1, 15); x1 ^= x0;
  x0 += x1; x1 = rotl32(x1, 26); x1 ^= x0;
  x0 += x1; x1 = rotl32(x1,  6); x1 ^= x0;
  x0 += k1; x1 += k2 + 1u;
  x0 += x1; x1 = rotl32(x1, 17); x1 ^= x0;
  x0 += x1; x1 = rotl32(x1, 29); x1 ^= x0;
  x0 += x1; x1 = rotl32(x1, 16); x1 ^= x0;
  x0 += x1; x1 = rotl32(x1, 24); x1 ^= x0;
  x0 += k2; x1 += k0 + 2u;
  x0 += x1; x1 = rotl32(x1, 13); x1 ^= x0;
  x0 += x1; x1 = rotl32(x1, 15); x1 ^= x0;
  x0 += x1; x1 = rotl32(x1, 26); x1 ^= x0;
  x0 += x1; x1 = rotl32(x1,  6); x1 ^= x0;
  x0 += k0; x1 += k1 + 3u;
  x0 += x1; x1 = rotl32(x1, 17); x1 ^= x0;
  x0 += x1; x1 = rotl32(x1, 29); x1 ^= x0;
  x0 += x1; x1 = rotl32(x1, 16); x1 ^= x0;
  x0 += x1; x1 = rotl32(x1, 24); x1 ^= x0;
  x0 += k1; x1 += k2 + 4u;
  x0 += x1; x1 = rotl32(x1, 13); x1 ^= x0;
  x0 += x1; x1 = rotl32(x1, 15); x1 ^= x0;
  x0 += x1; x1 = rotl32(x1, 26); x1 ^= x0;
  x0 += x1; x1 = rotl32(x1,  6); x1 ^= x0;
  x0 += k2; x1 += k0 + 5u;
}

// Repack W [1024 rows][256 k] row-major -> [k][u][gate] (float4 per (k,u)).
__global__ void repack_k(const float* __restrict__ eWh,
                         const float* __restrict__ dWi,
                         const float* __restrict__ dWh,
                         float* __restrict__ ws) {
  float* encW4 = (float*)((char*)ws + WS_ENCW4_OFF);
  float* decWi4 = (float*)((char*)ws + WS_DECWI4_OFF);
  float* decWh4 = (float*)((char*)ws + WS_DECWH4_OFF);
  const int n = blockIdx.x * blockDim.x + threadIdx.x;   // 65536 = 256k x 256u
  if (n >= 65536) return;
  const int k = n >> 8, u = n & 255;
#pragma unroll
  for (int g = 0; g < 4; ++g) {
    const int src = ((g << 8) + u) * 256 + k;
    const int dst = (n << 2) + g;
    encW4[dst] = eWh[src];
    decWi4[dst] = dWi[src];
    decWh4[dst] = dWh[src];
  }
}

__global__ void __launch_bounds__(1024)
ptrnet_kernel(const float* __restrict__ inp,    // [512][256][2]
              const float* __restrict__ eWi,    // [1024][2]
              const float* __restrict__ eBi, const float* __restrict__ eBh,
              const float* __restrict__ dBi, const float* __restrict__ dBh,
              int* __restrict__ out,            // [512][256]
              float* __restrict__ ws) {
  const int tid  = threadIdx.x;
  const int wave = tid >> 6, l = tid & 63;
  const int kq   = wave >> 2;               // encoder/prologue partition
  const int uw   = wave & 3;
  const int uP   = (uw << 6) | l;
  const int k4b  = kq << 4;
  const int bA   = tid >> 8;                // encoder P2 partition
  const int uA   = tid & 255;

  const int g    = blockIdx.x & 127;        // pair id
  const int H    = blockIdx.x >> 7;         // half: 0 = lo, 1 = hi
  const int b0   = g << 2;
  const int bG   = b0 + bA;
  const int ubase = H << 7;                 // owned u range [ubase, ubase+128)
  const int pbase = ubase ^ 128;            // partner's u base
  const int sbase = H << 7;                 // owned s range

  const v4f* encW4  = (const v4f*)((char*)ws + WS_ENCW4_OFF);
  const v4f* decWi4 = (const v4f*)((char*)ws + WS_DECWI4_OFF);
  const v4f* decWh4 = (const v4f*)((char*)ws + WS_DECWH4_OFF);
  v4f* encK4 = (v4f*)((char*)ws + WS_ENCK4_OFF);

  u64* hxAll  = (u64*)((char*)ws + WS_HX_OFF);
  u64* hxMe   = hxAll + (size_t)g * 1024 + (size_t)H * 512;
  u64* hxYo   = hxAll + (size_t)g * 1024 + (size_t)(1 - H) * 512;
  u64* amxAll = (u64*)((char*)ws + WS_AMX_OFF);
  u64* amxMe  = amxAll + (size_t)g * 16 + (size_t)H * 8;
  u64* amxYo  = amxAll + (size_t)g * 16 + (size_t)(1 - H) * 8;

  __shared__ __align__(16) float hsF[2][1024];   // h dbuf: [buf][b*256+u]
  __shared__ __align__(16) v4f dinV[256];        // dec_in [b][64 k4]
  __shared__ __align__(16) v4f red[17][256];     // partials; row 16 = LDS pad
  __shared__ unsigned char maskC[4][128];        // own s-half mask
  __shared__ float partV[4][2];
  __shared__ int   partI[4][2];
  __shared__ float oVs[4]; __shared__ int oIs[4];   // own half combined
  __shared__ float eVs[4]; __shared__ int eIs[4];   // partner half

  // ---- encoder activation constants (keyed by uA) ----
  const float ebi_ = eBi[uA] + eBh[uA];
  const float ebf_ = eBi[256 + uA] + eBh[256 + uA];
  const float ebg_ = eBi[512 + uA] + eBh[512 + uA];
  const float ebo_ = eBi[768 + uA] + eBh[768 + uA];
  const float wxi0 = eWi[2 * uA], wxi1 = eWi[2 * uA + 1];
  const float wxf0 = eWi[2 * (256 + uA)], wxf1 = eWi[2 * (256 + uA) + 1];
  const float wxg0 = eWi[2 * (512 + uA)], wxg1 = eWi[2 * (512 + uA) + 1];
  const float wxo0 = eWi[2 * (768 + uA)], wxo1 = eWi[2 * (768 + uA) + 1];

  hsF[0][tid] = 0.f;
  __syncthreads();

  float c = 0.f;
  int p = 0;

  // ---------------- encoder: 256 steps (R10-exact, redundant per pair) ------
  for (int t = 0; t < 256; ++t) {
    v4f a0 = (v4f)0.f, a1 = (v4f)0.f, a2 = (v4f)0.f, a3 = (v4f)0.f;
    const v4f* Wp = encW4 + uP;
    const v4f* hq = (const v4f*)&hsF[p][0];
#pragma unroll 2
    for (int kk = 0; kk < 16; ++kk) {
      const int k4 = k4b + kk;
      const v4f w0 = Wp[(k4 * 4 + 0) << 8];
      const v4f w1 = Wp[(k4 * 4 + 1) << 8];
      const v4f w2 = Wp[(k4 * 4 + 2) << 8];
      const v4f w3 = Wp[(k4 * 4 + 3) << 8];
      const v4f h0 = hq[k4];
      const v4f h1 = hq[64 + k4];
      const v4f h2 = hq[128 + k4];
      const v4f h3 = hq[192 + k4];
      a0 += w0 * h0.x + w1 * h0.y + w2 * h0.z + w3 * h0.w;
      a1 += w0 * h1.x + w1 * h1.y + w2 * h1.z + w3 * h1.w;
      a2 += w0 * h2.x + w1 * h2.y + w2 * h2.z + w3 * h2.w;
      a3 += w0 * h3.x + w1 * h3.y + w2 * h3.z + w3 * h3.w;
    }
    red[(kq << 2) | 0][uP] = a0;
    red[(kq << 2) | 1][uP] = a1;
    red[(kq << 2) | 2][uP] = a2;
    red[(kq << 2) | 3][uP] = a3;
    __syncthreads();
    const v4f gv = red[bA][uA] + red[4 + bA][uA] + red[8 + bA][uA] + red[12 + bA][uA];
    const float2 xv = *(const float2*)(inp + (((bG) << 8) + t) * 2);
    const float ai = gv.x + ebi_ + wxi0 * xv.x + wxi1 * xv.y;
    const float af = gv.y + ebf_ + wxf0 * xv.x + wxf1 * xv.y;
    const float ag = gv.z + ebg_ + wxg0 * xv.x + wxg1 * xv.y;
    const float ao = gv.w + ebo_ + wxo0 * xv.x + wxo1 * xv.y;
    const float iv = sigm(ai), fv = sigm(af), gva = tanhf(ag), ov = sigm(ao);
    c = fv * c + iv * gva;
    const float hn = ov * tanhf(c);
    hsF[p ^ 1][(bA << 8) | uA] = hn;
    ((float*)encK4)[(((bG << 6) + (uA >> 2)) << 10) + (t << 2) + (uA & 3)] = hn;
    __syncthreads();
    p ^= 1;
  }

  // ---------------- decoder setup: c handoff to split mapping ----------------
  float* creg = (float*)&red[0][0];
  creg[(bA << 8) | uA] = c;
  const int isP2 = tid < 512;
  const int bD = tid >> 7;                  // 0..3   (valid if isP2)
  const int uL = tid & 127;
  const int uD = ubase | uL;                // owned global u
  __syncthreads();
  float cD = 0.f, dbi2 = 0.f, dbf2 = 0.f, dbg2 = 0.f, dbo2 = 0.f;
  if (isP2) {
    cD = creg[(bD << 8) | uD];
    dbi2 = dBi[uD] + dBh[uD];
    dbf2 = dBi[256 + uD] + dBh[256 + uD];
    dbg2 = dBi[512 + uD] + dBh[512 + uD];
    dbo2 = dBi[768 + uD] + dBh[768 + uD];
  }
  // attn identity (valid for wave >= 8)
  const int aw  = wave - 8;
  const int bAt = aw >> 1;
  const int sL  = ((aw & 1) << 6) | l;
  const int sG  = sbase | sL;
  const int bGt = b0 + bAt;
  if (wave >= 8) maskC[bAt][sL] = 0;
  // Wh/Wi identity (valid for wave < 8)
  const int kqD  = wave >> 1;
  const int k4bD = kqD << 4;
  const int uPD  = ubase | ((wave & 1) << 6) | l;
  const float NEG_INF = __int_as_float((int)0xff800000);
  __syncthreads();                           // creg consumed; red free

  // ---- prologue: LSTM step 0 (din=0, Wi exact-0 skipped). Wh redundant
  //      16-wave full-u (identical values in both blocks); P2 split. ----
  {
    v4f a0 = (v4f)0.f, a1 = (v4f)0.f, a2 = (v4f)0.f, a3 = (v4f)0.f;
    const v4f* Wh = decWh4 + uP;
    const v4f* hq = (const v4f*)&hsF[p][0];
#pragma unroll 2
    for (int kk = 0; kk < 16; ++kk) {
      const int k4 = k4b + kk;
      const v4f w0 = Wh[(k4 * 4 + 0) << 8];
      const v4f w1 = Wh[(k4 * 4 + 1) << 8];
      const v4f w2 = Wh[(k4 * 4 + 2) << 8];
      const v4f w3 = Wh[(k4 * 4 + 3) << 8];
      const v4f h0 = hq[k4];
      const v4f h1 = hq[64 + k4];
      const v4f h2 = hq[128 + k4];
      const v4f h3 = hq[192 + k4];
      a0 += w0 * h0.x + w1 * h0.y + w2 * h0.z + w3 * h0.w;
      a1 += w0 * h1.x + w1 * h1.y + w2 * h1.z + w3 * h1.w;
      a2 += w0 * h2.x + w1 * h2.y + w2 * h2.z + w3 * h2.w;
      a3 += w0 * h3.x + w1 * h3.y + w2 * h3.z + w3 * h3.w;
    }
    red[(kq << 2) | 0][uP] = a0;
    red[(kq << 2) | 1][uP] = a1;
    red[(kq << 2) | 2][uP] = a2;
    red[(kq << 2) | 3][uP] = a3;
    __syncthreads();
    if (isP2) {
      const v4f gv = red[bD][uD] + red[4 + bD][uD] + red[8 + bD][uD] + red[12 + bD][uD];
      const float iv = sigm(gv.x + dbi2), fv = sigm(gv.y + dbf2);
      const float gva = tanhf(gv.z + dbg2), ov = sigm(gv.w + dbo2);
      cD = fv * cD + iv * gva;
      const float hn = ov * tanhf(cD);
      hsF[p ^ 1][(bD << 8) | uD] = hn;
      atomicExch(&hxMe[(bD << 7) | uL], pk(0xA5000000u, __float_as_uint(hn)));
      const unsigned pw = spinrd(&hxYo[(bD << 7) | uL], 0xA5000000u);
      hsF[p ^ 1][(bD << 8) | pbase | uL] = __uint_as_float(pw);
    }
    __syncthreads();
    p ^= 1;                                   // hsF[p] = full h_0
  }

#define WINNER(B, WI) { float _wv = oVs[B]; int _wi = oIs[B];                 \
    const float _ev = eVs[B]; const int _ei = eIs[B];                         \
    if (_ev > _wv || (_ev == _wv && _ei < _wi)) { _wi = _ei; }                \
    WI = _wi; }

  for (int t = 0; t < 256; ++t) {
    const unsigned tagA = 0xA5000001u + 2u * (unsigned)t;
    const unsigned tagH = 0xA5000002u + 2u * (unsigned)t;
    const v4f* hq = (const v4f*)&hsF[p][0];

    // ==== phase X: waves 0-7 Wh·h_t (u-half) ∥ waves 8-15 attention(t) ====
    if (wave < 8) {
      v4f a0 = (v4f)0.f, a1 = (v4f)0.f, a2 = (v4f)0.f, a3 = (v4f)0.f;
      const v4f* Wh = decWh4 + uPD;
#pragma unroll 2
      for (int kk = 0; kk < 16; ++kk) {
        const int k4 = k4bD + kk;
        const v4f w0 = Wh[(k4 * 4 + 0) << 8];
        const v4f w1 = Wh[(k4 * 4 + 1) << 8];
        const v4f w2 = Wh[(k4 * 4 + 2) << 8];
        const v4f w3 = Wh[(k4 * 4 + 3) << 8];
        const v4f h0 = hq[k4];
        const v4f h1 = hq[64 + k4];
        const v4f h2 = hq[128 + k4];
        const v4f h3 = hq[192 + k4];
        a0 += w0 * h0.x + w1 * h0.y + w2 * h0.z + w3 * h0.w;
        a1 += w0 * h1.x + w1 * h1.y + w2 * h1.z + w3 * h1.w;
        a2 += w0 * h2.x + w1 * h2.y + w2 * h2.z + w3 * h2.w;
        a3 += w0 * h3.x + w1 * h3.y + w2 * h3.z + w3 * h3.w;
      }
      red[(kqD << 2) | 0][uPD] = a0;
      red[(kqD << 2) | 1][uPD] = a1;
      red[(kqD << 2) | 2][uPD] = a2;
      red[(kqD << 2) | 3][uPD] = a3;
    } else {
      const int masked = maskC[bAt][sL];
      float sc = 0.f;
      if (!masked) {
        const v4f* E = encK4 + (bGt << 14) + sG;
        const v4f* hq2 = hq + (bAt << 6);
#pragma unroll 4
        for (int k4 = 0; k4 < 64; ++k4) {
          const v4f ev = E[k4 << 8];
          const v4f hv = hq2[k4];
          sc += ev.x * hv.x + ev.y * hv.y + ev.z * hv.z + ev.w * hv.w;
        }
      }
      unsigned bits;
      {
        unsigned kk0 = 0u, kk1 = (unsigned)t;
        tf2(0u, 42u, kk0, kk1);
        unsigned y0 = 0u, y1 = (unsigned)((bGt << 8) + sG);
        tf2(kk0, kk1, y0, y1);
        bits = y0 ^ y1;
      }
      const float fr = __uint_as_float((bits >> 9) | 0x3f800000u) - 1.0f;
      const float uu = (fr > 0.f) ? fr : 1.17549435e-38f;
      const float gum = -logf(-logf(uu));
      float bv = masked ? NEG_INF : (sc + gum);
      int bi = sG;
#pragma unroll
      for (int off = 32; off; off >>= 1) {
        const float ov2 = __shfl_xor(bv, off, 64);
        const int oi2 = __shfl_xor(bi, off, 64);
        if (ov2 > bv || (ov2 == bv && oi2 < bi)) { bv = ov2; bi = oi2; }
      }
      if (l == 0) { partV[bAt][aw & 1] = bv; partI[bAt][aw & 1] = bi; }
    }
    __syncthreads();                          // S1: red-Wh + partials ready

    // ==== local combine + publish (tid 0-3); spin partner (tid 64-71) ====
    if (tid < 4) {
      float v0 = partV[tid][0]; int i0 = partI[tid][0];
      const float v1 = partV[tid][1];
      if (v1 > v0) { v0 = v1; i0 = partI[tid][1]; }   // strict >: lower s kept
      oVs[tid] = v0; oIs[tid] = i0;
      atomicExch(&amxMe[tid * 2 + 0], pk(tagA, __float_as_uint(v0)));
      atomicExch(&amxMe[tid * 2 + 1], pk(tagA, (unsigned)i0));
    }
    if (tid >= 64 && tid < 72) {
      const int j = tid - 64;                 // b*2 + {val,idx}
      const unsigned pw = spinrd(&amxYo[j], tagA);
      if (j & 1) eIs[j >> 1] = (int)pw;
      else       eVs[j >> 1] = __uint_as_float(pw);
    }
    __syncthreads();                          // S2: both halves' results ready

    // ==== winner, mask, out, din staging ====
    if (wave >= 8) {
      int wi; WINNER(bAt, wi);
      if (sG == wi) maskC[bAt][sL] = 1;
    }
    if (H == 0 && tid < 4) {
      int wi; WINNER(tid, wi);
      out[((b0 + tid) << 8) + t] = wi;
    }
    if (tid < 256) {
      const int bb = tid >> 6, k4s = tid & 63;
      int wi; WINNER(bb, wi);
      dinV[tid] = encK4[((((b0 + bb) << 6) | k4s) << 8) + wi];
    }
    __syncthreads();                          // S3: din/mask ready

    if (t == 255) break;                      // last index emitted

    // ==== Wi·din sweep (waves 0-7, continue chain from red — lossless) ====
    if (wave < 8) {
      v4f a0 = red[(kqD << 2) | 0][uPD];
      v4f a1 = red[(kqD << 2) | 1][uPD];
      v4f a2 = red[(kqD << 2) | 2][uPD];
      v4f a3 = red[(kqD << 2) | 3][uPD];
      const v4f* Wi = decWi4 + uPD;
#pragma unroll 2
      for (int kk = 0; kk < 16; ++kk) {
        const int k4 = k4bD + kk;
        const v4f w0 = Wi[(k4 * 4 + 0) << 8];
        const v4f w1 = Wi[(k4 * 4 + 1) << 8];
        const v4f w2 = Wi[(k4 * 4 + 2) << 8];
        const v4f w3 = Wi[(k4 * 4 + 3) << 8];
        const v4f d0 = dinV[k4];
        const v4f d1 = dinV[64 + k4];
        const v4f d2 = dinV[128 + k4];
        const v4f d3 = dinV[192 + k4];
        a0 += w0 * d0.x + w1 * d0.y + w2 * d0.z + w3 * d0.w;
        a1 += w0 * d1.x + w1 * d1.y + w2 * d1.z + w3 * d1.w;
        a2 += w0 * d2.x + w1 * d2.y + w2 * d2.z + w3 * d2.w;
        a3 += w0 * d3.x + w1 * d3.y + w2 * d3.z + w3 * d3.w;
      }
      red[(kqD << 2) | 0][uPD] = a0;
      red[(kqD << 2) | 1][uPD] = a1;
      red[(kqD << 2) | 2][uPD] = a2;
      red[(kqD << 2) | 3][uPD] = a3;
    }
    __syncthreads();                          // S4: full partials ready

    // ==== P2 (split) -> h_{t+1}; publish + fetch partner half ====
    if (isP2) {
      const v4f gv = red[bD][uD] + red[4 + bD][uD] + red[8 + bD][uD] + red[12 + bD][uD];
      const float iv = sigm(gv.x + dbi2), fv = sigm(gv.y + dbf2);
      const float gva = tanhf(gv.z + dbg2), ov = sigm(gv.w + dbo2);
      cD = fv * cD + iv * gva;
      const float hn = ov * tanhf(cD);
      hsF[p ^ 1][(bD << 8) | uD] = hn;
      atomicExch(&hxMe[(bD << 7) | uL], pk(tagH, __float_as_uint(hn)));
      const unsigned pw = spinrd(&hxYo[(bD << 7) | uL], tagH);
      hsF[p ^ 1][(bD << 8) | pbase | uL] = __uint_as_float(pw);
    }
    __syncthreads();                          // S5: full h_{t+1} ready
    p ^= 1;
  }
#undef WINNER
}

extern "C" void kernel_launch(void* const* d_in, const int* in_sizes, int n_in,
                              void* d_out, int out_size, void* d_ws, size_t ws_size,
                              hipStream_t stream) {
  (void)in_sizes; (void)n_in; (void)out_size;
  if (ws_size < WS_NEEDED) return;   // need ~139 MB scratch

  const float* inp = (const float*)d_in[0];
  const float* eWi = (const float*)d_in[1];
  const float* eWh = (const float*)d_in[2];
  const float* eBi = (const float*)d_in[3];
  const float* eBh = (const float*)d_in[4];
  const float* dWi = (const float*)d_in[5];
  const float* dWh = (const float*)d_in[6];
  const float* dBi = (const float*)d_in[7];
  const float* dBh = (const float*)d_in[8];
  int* out = (int*)d_out;
  float* wsf = (float*)d_ws;

  // zero the sync region every launch: fresh tags, no ABA across graph replays
  hipMemsetAsync((char*)d_ws + WS_HX_OFF, 0, WS_SYNC_BYTES, stream);
  hipLaunchKernelGGL(repack_k, dim3(256), dim3(256), 0, stream, eWh, dWi, dWh, wsf);
  hipLaunchKernelGGL(ptrnet_kernel, dim3(256), dim3(1024), 0, stream,
                     inp, eWi, eBi, eBh, dBi, dBh, out, wsf);
}